// Round 7
// 875.359 us; speedup vs baseline: 1.0170x; 1.0170x over previous
//
#include <hip/hip_runtime.h>
#include <math.h>

#define TOTF   12240
#define NU     3060          // TOTF/4 float4 features
#define KTILE  128
#define NTILES 96            // ceil(3060/32) tiles of 32 float4-chunks
#define ASTRIDE 136          // bf16 elems per LDS row (128 + 8 pad, keeps 16B align)
#define MQ     16            // queries per block
#define NTHR   512

typedef float f32x4  __attribute__((ext_vector_type(4)));
typedef short bf16x8 __attribute__((ext_vector_type(8)));

// center + 6 faces (reference order)
__constant__ int OFF7[7][3] = {
    {0,0,0},{1,0,0},{-1,0,0},{0,1,0},{0,-1,0},{0,0,1},{0,0,-1}
};
// FACE(6) then CORNER(8): BASIC_ST row r -> spat = r>>1, tt = (r&1)? -1:+1
__constant__ int SPAT14[14][3] = {
    {1,0,0},{-1,0,0},{0,1,0},{0,-1,0},{0,0,1},{0,0,-1},
    {1,1,1},{-1,-1,-1},{1,-1,-1},{-1,1,1},{1,1,-1},{-1,-1,1},{1,-1,1},{-1,1,-1}
};
__constant__ int CORN8[8][3] = {
    {1,1,1},{-1,-1,-1},{1,-1,-1},{-1,1,1},{1,1,-1},{-1,-1,1},{1,-1,1},{-1,1,-1}
};
__constant__ int EXPT[11] = {-64,-8,-4,-2,-1,0,1,2,4,8,64};

static __device__ __forceinline__ unsigned short f2bf(float f) {
    unsigned int u = __float_as_uint(f);
    u += 0x7fffu + ((u >> 16) & 1u);          // round-to-nearest-even
    return (unsigned short)(u >> 16);
}

// ---- pre-kernel: Wt[j][k] = bf16(w_down[k][j] * rms_scale[k]) --------------
__global__ __launch_bounds__(256)
void wconv_kernel(const float* __restrict__ w, const float* __restrict__ s,
                  unsigned short* __restrict__ Wt) {
    int id = blockIdx.x * 256 + threadIdx.x;
    if (id < TOTF * 64) {
        int k = id >> 6, j = id & 63;
        Wt[j * TOTF + k] = f2bf(w[id] * s[k]);
    }
}

// ---- main fused gather + rmsnorm + GEMM + head -----------------------------
// 2-phase software pipeline: per tile {barrier; issue loads(t+1)->regs;
// MFMA(t) from LDS buf[t&1]; relu/cvt/ds_write(t+1) into buf[t&1^1]}.
// No VMEM outstanding at any barrier; gather latency hides under MFMA+LDS.
__global__ __launch_bounds__(NTHR)
void st_fused_kernel(const float* __restrict__ pos, const float* __restrict__ dirv,
                     const float* __restrict__ t,
                     const float* __restrict__ tb0, const float* __restrict__ tb1,
                     const float* __restrict__ tb2, const float* __restrict__ tb3,
                     const float* __restrict__ st1, const float* __restrict__ st2,
                     const float* __restrict__ tf3,
                     const unsigned short* __restrict__ Wt,
                     const float* __restrict__ w_final, const float* __restrict__ b_final,
                     float* __restrict__ out, int N)
{
    __shared__ unsigned int offs_s[172 * MQ];                        // 11008 B (uint32 byte-offsets)
    __shared__ __align__(16) unsigned short Atile[2][MQ * ASTRIDE];  //  8704 B (dbuf)
    __shared__ __align__(16) unsigned short Wtile[2][64 * ASTRIDE];  // 34816 B (dbuf)
    __shared__ float ssq_s[MQ];
    __shared__ float inv_s[MQ];

    const int tid = threadIdx.x;
    const int q0  = blockIdx.x * MQ;
    const int q   = tid & 15;            // this thread's query (gather role)
    const int e   = tid >> 4;            // this thread's float4-chunk within tile [0,32)
    const int qg  = min(q0 + q, N - 1);

    // ---- phase 0: per-(q,entry) byte offsets (table base re-attached at load) ----
    {
        const float px = pos[qg*3+0], py = pos[qg*3+1], pz = pos[qg*3+2];
        const float tv = t[qg];
        const int b0x=(int)(px*127.f), b0y=(int)(py*127.f), b0z=(int)(pz*127.f);
        const int b1x=(int)(px*63.f),  b1y=(int)(py*63.f),  b1z=(int)(pz*63.f);
        const int b2x=(int)(px*31.f),  b2y=(int)(py*31.f),  b2z=(int)(pz*31.f);
        const int b3x=(int)(px*15.f),  b3y=(int)(py*15.f),  b3z=(int)(pz*15.f);
        const int i15=(int)(tv*15.f),  i63=(int)(tv*63.f);   // t_idx broadcast quirk

        for (int ent = tid >> 4; ent < 172; ent += 32) {
            unsigned off;
            if (ent < 7) {
                int ix=(b0x+OFF7[ent][0]+128)&127, iy=(b0y+OFF7[ent][1]+128)&127, iz=(b0z+OFF7[ent][2]+128)&127;
                off = (unsigned)(((ix*128+iy)*128+iz) * 64);                       // 16 f
            } else if (ent < 14) {
                int l=ent-7;
                int ix=(b1x+OFF7[l][0]+64)&63, iy=(b1y+OFF7[l][1]+64)&63, iz=(b1z+OFF7[l][2]+64)&63;
                off = (unsigned)(((ix*64+iy)*64+iz) * 256);                        // 64 f
            } else if (ent < 21) {
                int l=ent-14;
                int ix=(b2x+OFF7[l][0]+32)&31, iy=(b2y+OFF7[l][1]+32)&31, iz=(b2z+OFF7[l][2]+32)&31;
                off = (unsigned)(((ix*32+iy)*32+iz) * 1024);                       // 256 f
            } else if (ent < 28) {
                int l=ent-21;
                int ix=(b3x+OFF7[l][0]+16)&15, iy=(b3y+OFF7[l][1]+16)&15, iz=(b3z+OFF7[l][2]+16)&15;
                off = (unsigned)(((ix*16+iy)*16+iz) * 4096);                       // 1024 f
            } else if (ent < 56) {
                int r=ent-28, s=r>>1, tt=(r&1)?-1:1;
                int ix=(i15+SPAT14[s][0]+16)&15, iy=(i15+SPAT14[s][1]+16)&15, iz=(i15+SPAT14[s][2]+16)&15;
                int it=(i63+tt+64)&63;
                off = (unsigned)((((ix*16+iy)*16+iz)*64+it) * 256);                // 64 f
            } else if (ent < 84) {
                int r=ent-56, s=r>>1, tt=(r&1)?-1:1;
                int ix=(i15+SPAT14[s][0]+64)&63, iy=(i15+SPAT14[s][1]+64)&63, iz=(i15+SPAT14[s][2]+64)&63;
                int it=(i63+tt+64)&63;
                off = (unsigned)((((ix*64+iy)*64+iz)*64+it) * 32);                 // 8 f
            } else {
                int r=ent-84, c=r/11, ti=r-c*11;
                int ix=(i15+CORN8[c][0]+4)&3, iy=(i15+CORN8[c][1]+4)&3, iz=(i15+CORN8[c][2]+4)&3;
                int it=(i63+EXPT[ti]+65536)&65535;
                off = (unsigned)((((ix*4+iy)*4+iz)*65536+it) * 32);                // 8 f
            }
            offs_s[ent * MQ + q] = off;
        }
    }
    if (tid < MQ) ssq_s[tid] = 0.f;
    __syncthreads();                            // offs_s + ssq_s visible

    // MFMA roles
    const int lane = tid & 63, w = tid >> 6;
    const int jt = w & 3, ksp = w >> 2;          // 4 j-tiles x 2 K-split halves
    const int mrow = lane & 15, kq = (lane >> 4) * 8;
    // W-staging roles: 1024 uint4 chunks/tile -> 2 per thread
    const int wj = tid >> 4;                     // W row [0,32); +32 for second load
    const int wc = tid & 15;                     // chunk within row [0,16)
    f32x4 acc = {0.f, 0.f, 0.f, 0.f};
    float ss = 0.f;

    float4 av; uint4 wva, wvb;                   // in-flight tile registers

    // issue all global loads for tile tt into registers
    auto LOADS = [&](int tt) {
        const int u = tt * 32 + e;
        av = make_float4(0.f, 0.f, 0.f, 0.f);
        if (u < NU) {
            unsigned long long a;
            if (u < 28)        { a = (unsigned long long)tb0 + offs_s[(u >> 2) * MQ + q]          + (unsigned)((u & 3)   * 16); }
            else if (u < 140)  { int x = u - 28;   a = (unsigned long long)tb1 + offs_s[(7  + (x >> 4)) * MQ + q] + (unsigned)((x & 15)  * 16); }
            else if (u < 588)  { int x = u - 140;  a = (unsigned long long)tb2 + offs_s[(14 + (x >> 6)) * MQ + q] + (unsigned)((x & 63)  * 16); }
            else if (u < 2380) { int x = u - 588;  a = (unsigned long long)tb3 + offs_s[(21 + (x >> 8)) * MQ + q] + (unsigned)((x & 255) * 16); }
            else if (u < 2828) { int x = u - 2380; a = (unsigned long long)st1 + offs_s[(28 + (x >> 4)) * MQ + q] + (unsigned)((x & 15)  * 16); }
            else if (u < 2884) { int x = u - 2828; a = (unsigned long long)st2 + offs_s[(56 + (x >> 1)) * MQ + q] + (unsigned)((x & 1)   * 16); }
            else               { int x = u - 2884; a = (unsigned long long)tf3 + offs_s[(84 + (x >> 1)) * MQ + q] + (unsigned)((x & 1)   * 16); }
            av = *(const float4*)(uintptr_t)a;
        }
        // W: rows wj and wj+32, cols [tt*128, tt*128+128). Clamp keeps tail in-bounds;
        // clamped (duplicate) W cols pair only with zero A cols (u>=NU) -> harmless.
        const int kg = min(tt * KTILE + wc * 8, TOTF - 8);
        wva = *(const uint4*)(Wt + wj * TOTF + kg);
        wvb = *(const uint4*)(Wt + (wj + 32) * TOTF + kg);
    };

    // relu + sumsq + bf16-pack + LDS write into buffer b (waits on LOADS regs)
    auto PWRITE = [&](int b) {
        float r0 = fmaxf(av.x, 0.f), r1 = fmaxf(av.y, 0.f);
        float r2 = fmaxf(av.z, 0.f), r3 = fmaxf(av.w, 0.f);
        ss += r0*r0 + r1*r1 + r2*r2 + r3*r3;
        ushort4 pk;
        pk.x = f2bf(r0); pk.y = f2bf(r1); pk.z = f2bf(r2); pk.w = f2bf(r3);
        *(ushort4*)&Atile[b][q * ASTRIDE + e * 4] = pk;
        *(uint4*)&Wtile[b][wj * ASTRIDE + wc * 8] = wva;
        *(uint4*)&Wtile[b][(wj + 32) * ASTRIDE + wc * 8] = wvb;
    };

    // prologue: fill buffer 0
    LOADS(0);
    PWRITE(0);

    for (int tile = 0; tile < NTILES; ++tile) {
        const int cur = tile & 1;
        __syncthreads();                         // buf[cur] writes visible; no VMEM outstanding
        if (tile + 1 < NTILES) LOADS(tile + 1);  // fire next tile's gathers under MFMA
        const unsigned short* At = Atile[cur];
        const unsigned short* Bt = Wtile[cur];
        #pragma unroll
        for (int s2 = 0; s2 < 2; ++s2) {
            const int kk = ksp * 64 + s2 * 32 + kq;
            bf16x8 avf = *(const bf16x8*)&At[mrow * ASTRIDE + kk];
            bf16x8 bvf = *(const bf16x8*)&Bt[(jt * 16 + mrow) * ASTRIDE + kk];
            acc = __builtin_amdgcn_mfma_f32_16x16x32_bf16(avf, bvf, acc, 0, 0, 0);
        }
        if (tile + 1 < NTILES) PWRITE(cur ^ 1);  // vmcnt wait lands here, after MFMA
    }

    // ---- epilogue ----
    __syncthreads();                       // Atile free; reuse as h_s[16][64]
    atomicAdd(&ssq_s[q], ss);
    float* h_s = (float*)Atile;
    if (ksp == 0) {
        #pragma unroll
        for (int r = 0; r < 4; ++r)
            h_s[((lane >> 4) * 4 + r) * 64 + jt * 16 + (lane & 15)] = acc[r];
    }
    __syncthreads();
    if (ksp == 1) {
        #pragma unroll
        for (int r = 0; r < 4; ++r)
            h_s[((lane >> 4) * 4 + r) * 64 + jt * 16 + (lane & 15)] += acc[r];
    }
    __syncthreads();
    if (tid < MQ) {
        const float RSQ = 9.0395480320866816e-03f;   // 12240^-0.5
        inv_s[tid] = 1.0f / (sqrtf(ssq_s[tid]) * RSQ + 1e-8f);
    }
    __syncthreads();
    if (tid < 64) {
        const int qq = tid >> 2, o = tid & 3;
        const int qqg = q0 + qq;
        if (qqg < N) {
            const float inv = inv_s[qq];
            float s = b_final[o];
            float hs = 0.f;
            #pragma unroll 8
            for (int j = 0; j < 64; ++j)
                hs += fmaxf(h_s[qq * 64 + j], 0.f) * w_final[j * 4 + o];
            s += hs * inv;                            // relu(h*inv) = inv*relu(h), inv>0
            s += dirv[qqg*3+0] * w_final[64*4 + o];
            s += dirv[qqg*3+1] * w_final[65*4 + o];
            s += dirv[qqg*3+2] * w_final[66*4 + o];
            s += t[qqg]        * w_final[67*4 + o];
            out[qqg * 4 + o] = 1.0f / (1.0f + expf(-s));
        }
    }
}

extern "C" void kernel_launch(void* const* d_in, const int* in_sizes, int n_in,
                              void* d_out, int out_size, void* d_ws, size_t ws_size,
                              hipStream_t stream) {
    const float* pos  = (const float*)d_in[0];
    const float* dirv = (const float*)d_in[1];
    const float* t    = (const float*)d_in[2];
    const float* tb0  = (const float*)d_in[3];
    const float* tb1  = (const float*)d_in[4];
    const float* tb2  = (const float*)d_in[5];
    const float* tb3  = (const float*)d_in[6];
    const float* st1  = (const float*)d_in[7];
    const float* st2  = (const float*)d_in[8];
    const float* tf3  = (const float*)d_in[9];
    const float* rs   = (const float*)d_in[10];
    const float* wd   = (const float*)d_in[11];
    const float* wf   = (const float*)d_in[12];
    const float* bf   = (const float*)d_in[13];
    float* out = (float*)d_out;
    unsigned short* Wt = (unsigned short*)d_ws;      // 64*12240*2 = 1.57 MB

    const int N = in_sizes[2];                       // 8192
    wconv_kernel<<<dim3((TOTF * 64 + 255) / 256), dim3(256), 0, stream>>>(wd, rs, Wt);
    st_fused_kernel<<<dim3((N + MQ - 1) / MQ), dim3(NTHR), 0, stream>>>(
        pos, dirv, t, tb0, tb1, tb2, tb3, st1, st2, tf3, Wt, wf, bf, out, N);
}